// Round 9
// baseline (567.575 us; speedup 1.0000x reference)
//
#include <hip/hip_runtime.h>

#define SEQ 288
#define INP 7
#define HID 128
#define TLEN 288
#define OUTD 3
#define XW (SEQ * INP)   // 2016
#define BPB 2            // batches per block (2 blocks co-resident per CU)

typedef _Float16 f16x8 __attribute__((ext_vector_type(8)));
typedef float f32x4 __attribute__((ext_vector_type(4)));

__device__ __forceinline__ float fast_sigmoid(float x) {
    float e = __expf(-x);
    return __builtin_amdgcn_rcpf(1.0f + e);
}
__device__ __forceinline__ float fast_tanh(float x) {
    float e = __expf(-2.0f * x);
    return 2.0f * __builtin_amdgcn_rcpf(1.0f + e) - 1.0f;
}

// DPP-based full-wave (64) sum -> uniform scalar.
template<int CTRL, int RM>
__device__ __forceinline__ float dpp_add(float v) {
    int t = __builtin_amdgcn_update_dpp(0, __float_as_int(v), CTRL, RM, 0xF, true);
    return v + __int_as_float(t);
}
__device__ __forceinline__ float wave_sum(float v) {
    v = dpp_add<0xB1, 0xF>(v);   // quad_perm [1,0,3,2]
    v = dpp_add<0x4E, 0xF>(v);   // quad_perm [2,3,0,1]
    v = dpp_add<0x124, 0xF>(v);  // row_ror:4
    v = dpp_add<0x128, 0xF>(v);  // row_ror:8
    v = dpp_add<0x142, 0xA>(v);  // row_bcast15
    v = dpp_add<0x143, 0xC>(v);  // row_bcast31 -> lane63 total
    return __int_as_float(__builtin_amdgcn_readlane(__float_as_int(v), 63));
}

// Redistribute D-fragment (rows 0-3 -> lanes 0-15, regs 0-3) so that
// lane L ends up holding the value for (b = L>>4, col = L&15).
__device__ __forceinline__ float redist4(f32x4 s) {
    int r0 = __float_as_int(s[0]), r1 = __float_as_int(s[1]);
    int r2 = __float_as_int(s[2]), r3 = __float_as_int(s[3]);
    auto p02 = __builtin_amdgcn_permlane32_swap(r0, r2, false, false);
    auto p13 = __builtin_amdgcn_permlane32_swap(r1, r3, false, false);
#if __has_builtin(__builtin_amdgcn_permlane16_swap)
    auto q = __builtin_amdgcn_permlane16_swap(p02[0], p13[0], false, false);
    return __int_as_float(q[0]);
#else
    float n0 = __int_as_float(p02[0]);
    float n1 = __int_as_float(p13[0]);
    int lane = threadIdx.x & 63;
    float tshf = __shfl(n1, lane ^ 16);
    return (lane & 16) ? tshf : n0;
#endif
}

__global__ __launch_bounds__(512, 2)
void enc_dec_kernel(const float* __restrict__ x,
                    const float* __restrict__ eWih, const float* __restrict__ eWhh,
                    const float* __restrict__ ebih, const float* __restrict__ ebhh,
                    const float* __restrict__ dWih, const float* __restrict__ dWhh,
                    const float* __restrict__ dbih, const float* __restrict__ dbhh,
                    const float* __restrict__ oW,  const float* __restrict__ ob,
                    float* __restrict__ out)
{
    // h double-buffer in A-fragment layout [dbuf][kc(4)][row=batch(16)][ke(40 pad)]
    // rows BPB..15 stay zero.
    __shared__ __align__(16) _Float16 hbuf[2][4][16][40];
    // pre-converted x + constant-1 (bias rider): [t][b][8], j=7 == 1.0
    __shared__ __align__(16) _Float16 xf16[SEQ + 1][BPB][8];
    __shared__ float zbl[4][BPB][HID];   // decoder zbase handoff [gate][b][u]
    __shared__ float cl[BPB][HID];       // c_enc handoff [b][u]

    const int tid  = threadIdx.x;
    const int wave = tid >> 6;
    const int lane = tid & 63;
    const int col  = lane & 15;        // A-row (batch) / B n-col (unit) index
    const int grp  = lane >> 4;        // k-chunk 0..3; post-redist: batch row
    const int u    = wave * 16 + col;  // this lane's unit column
    const int bb   = grp;              // this lane's batch row (post-redist)
    const int b0   = blockIdx.x * BPB;

    // ---- prologue: zero hbuf + xf16 pad, build xf16 ----
    {
        _Float16* hb = &hbuf[0][0][0][0];
        for (int i = tid; i < 2 * 4 * 16 * 40; i += 512) hb[i] = (_Float16)0.f;
        _Float16* xp = &xf16[SEQ][0][0];
        if (tid < BPB * 8) xp[tid] = (_Float16)0.f;
    }
    for (int i = tid; i < BPB * XW; i += 512) {
        int b = i / XW, r = i % XW;
        int t = r / INP, j = r % INP;
        xf16[t][b][j] = (_Float16)x[(size_t)(b0 + b) * XW + r];
    }
    for (int i = tid; i < SEQ * BPB; i += 512)
        xf16[i / BPB][i % BPB][7] = (_Float16)1.0f;

    // ---- encoder weights as persistent B-fragments ----
    // kc 0..3: Whh (k = kc*32 + grp*8 + e); kc 4: Wih cols j<7, bias at j==7
    f16x8 wfrag[4][5];
    #pragma unroll
    for (int gt = 0; gt < 4; ++gt) {
        const int row = gt * HID + u;
        #pragma unroll
        for (int kc = 0; kc < 4; ++kc) {
            const float* wr = eWhh + (size_t)row * HID + kc * 32 + grp * 8;
            f16x8 wf;
            #pragma unroll
            for (int e = 0; e < 8; ++e) wf[e] = (_Float16)wr[e];
            wfrag[gt][kc] = wf;
        }
        {
            f16x8 wf;
            #pragma unroll
            for (int e = 0; e < 8; ++e) {
                int j = grp * 8 + e;
                float v = 0.f;
                if (j < INP)       v = eWih[(size_t)row * INP + j];
                else if (j == 7)   v = ebih[row] + ebhh[row];
                wf[e] = (_Float16)v;
            }
            wfrag[gt][4] = wf;
        }
    }

    __syncthreads();   // xf16 + hbuf ready

    float cc = 0.f;    // c state for this lane's (bb, u)
    const f32x4 zero = (f32x4){0.f, 0.f, 0.f, 0.f};

    // accX: (x_t @ Wih.T + bias) for the CURRENT step, computed one step ahead.
    f32x4 accX[4];
    {
        f16x8 ax0 = *(const f16x8*)&xf16[0][col & 1][0];
        #pragma unroll
        for (int gt = 0; gt < 4; ++gt)
            accX[gt] = __builtin_amdgcn_mfma_f32_16x16x32_f16(ax0, wfrag[gt][4], zero, 0, 0, 0);
    }

    // ---------------- encoder: 288 steps, unrolled x2 ----------------
    #define ENC_STEP(T, CUR, NXT)                                                     \
    {                                                                                 \
        f16x8 af0 = *(const f16x8*)&hbuf[CUR][0][col][grp * 8];                       \
        f16x8 af1 = *(const f16x8*)&hbuf[CUR][1][col][grp * 8];                       \
        f16x8 af2 = *(const f16x8*)&hbuf[CUR][2][col][grp * 8];                       \
        f16x8 af3 = *(const f16x8*)&hbuf[CUR][3][col][grp * 8];                       \
        f32x4 acc[4];                                                                 \
        _Pragma("unroll")                                                             \
        for (int gt = 0; gt < 4; ++gt) {                                              \
            acc[gt] = __builtin_amdgcn_mfma_f32_16x16x32_f16(af0, wfrag[gt][0], accX[gt], 0, 0, 0); \
            acc[gt] = __builtin_amdgcn_mfma_f32_16x16x32_f16(af1, wfrag[gt][1], acc[gt], 0, 0, 0);  \
            acc[gt] = __builtin_amdgcn_mfma_f32_16x16x32_f16(af2, wfrag[gt][2], acc[gt], 0, 0, 0);  \
            acc[gt] = __builtin_amdgcn_mfma_f32_16x16x32_f16(af3, wfrag[gt][3], acc[gt], 0, 0, 0);  \
        }                                                                             \
        f16x8 axn = *(const f16x8*)&xf16[(T) + 1][col & 1][0];                        \
        _Pragma("unroll")                                                             \
        for (int gt = 0; gt < 4; ++gt)                                                \
            accX[gt] = __builtin_amdgcn_mfma_f32_16x16x32_f16(axn, wfrag[gt][4], zero, 0, 0, 0);    \
        float zi = redist4(acc[0]);                                                   \
        float zf = redist4(acc[1]);                                                   \
        float zg = redist4(acc[2]);                                                   \
        float zo = redist4(acc[3]);                                                   \
        float si = fast_sigmoid(zi);                                                  \
        float sf = fast_sigmoid(zf);                                                  \
        float tg = fast_tanh(zg);                                                     \
        float so = fast_sigmoid(zo);                                                  \
        cc = sf * cc + si * tg;                                                       \
        float h = so * fast_tanh(cc);                                                 \
        if (bb < BPB)                                                                 \
            hbuf[NXT][u >> 5][bb][u & 31] = (_Float16)h;                              \
        __syncthreads();                                                              \
    }

    for (int t = 0; t < SEQ; t += 2) {
        ENC_STEP(t, 0, 1)
        ENC_STEP(t + 1, 1, 0)
    }
    #undef ENC_STEP
    // h_enc in hbuf[0]; c_enc = cc per lane (bb, u).

    // ---------------- decoder zbase (all 8 waves) ----------------
    #pragma unroll
    for (int gt = 0; gt < 4; ++gt) {
        const int row = gt * HID + u;
        #pragma unroll
        for (int kc = 0; kc < 4; ++kc) {
            const float* wr = dWhh + (size_t)row * HID + kc * 32 + grp * 8;
            f16x8 wf;
            #pragma unroll
            for (int e = 0; e < 8; ++e) wf[e] = (_Float16)wr[e];
            wfrag[gt][kc] = wf;
        }
    }
    {
        f16x8 af0 = *(const f16x8*)&hbuf[0][0][col][grp * 8];
        f16x8 af1 = *(const f16x8*)&hbuf[0][1][col][grp * 8];
        f16x8 af2 = *(const f16x8*)&hbuf[0][2][col][grp * 8];
        f16x8 af3 = *(const f16x8*)&hbuf[0][3][col][grp * 8];
        #pragma unroll
        for (int gt = 0; gt < 4; ++gt) {
            float bd = dbih[gt * HID + u] + dbhh[gt * HID + u];
            f32x4 acc = (f32x4){bd, bd, bd, bd};
            acc = __builtin_amdgcn_mfma_f32_16x16x32_f16(af0, wfrag[gt][0], acc, 0, 0, 0);
            acc = __builtin_amdgcn_mfma_f32_16x16x32_f16(af1, wfrag[gt][1], acc, 0, 0, 0);
            acc = __builtin_amdgcn_mfma_f32_16x16x32_f16(af2, wfrag[gt][2], acc, 0, 0, 0);
            acc = __builtin_amdgcn_mfma_f32_16x16x32_f16(af3, wfrag[gt][3], acc, 0, 0, 0);
            float zv = redist4(acc);
            if (bb < BPB) zbl[gt][bb][u] = zv;
        }
        if (bb < BPB) cl[bb][u] = cc;
    }
    __syncthreads();

    // ---------------- decoder: 1 wave per batch row, no barriers ----------
    if (wave >= BPB) return;
    {
        const int b = wave;
        const int u0 = lane, u1 = 64 + lane;
        float zb0[4], zb1[4], wd0[4][3], wd1[4][3];
        #pragma unroll
        for (int gt = 0; gt < 4; ++gt) {
            zb0[gt] = zbl[gt][b][u0];
            zb1[gt] = zbl[gt][b][u1];
            #pragma unroll
            for (int j = 0; j < 3; ++j) {
                wd0[gt][j] = dWih[(size_t)(gt * HID + u0) * 3 + j];
                wd1[gt][j] = dWih[(size_t)(gt * HID + u1) * 3 + j];
            }
        }
        const float c0 = cl[b][u0], c1 = cl[b][u1];
        float ow0[3], ow1[3];
        #pragma unroll
        for (int j = 0; j < 3; ++j) {
            ow0[j] = oW[j * HID + u0];
            ow1[j] = oW[j * HID + u1];
        }
        const float ob0 = ob[0], ob1 = ob[1], ob2 = ob[2];

        float y0 = 0.f, y1 = 0.f, y2 = 0.f;
        float* orow = out + (size_t)(b0 + b) * (TLEN * OUTD);

        for (int t = 0; t < TLEN; ++t) {
            float z0[4], z1[4];
            #pragma unroll
            for (int gt = 0; gt < 4; ++gt) {
                z0[gt] = zb0[gt] + wd0[gt][0] * y0 + wd0[gt][1] * y1 + wd0[gt][2] * y2;
                z1[gt] = zb1[gt] + wd1[gt][0] * y0 + wd1[gt][1] * y1 + wd1[gt][2] * y2;
            }
            float si0 = fast_sigmoid(z0[0]), sf0 = fast_sigmoid(z0[1]);
            float tg0 = fast_tanh(z0[2]),    so0 = fast_sigmoid(z0[3]);
            float si1 = fast_sigmoid(z1[0]), sf1 = fast_sigmoid(z1[1]);
            float tg1 = fast_tanh(z1[2]),    so1 = fast_sigmoid(z1[3]);
            float cd0 = sf0 * c0 + si0 * tg0;
            float cd1 = sf1 * c1 + si1 * tg1;
            float hd0 = so0 * fast_tanh(cd0);
            float hd1 = so1 * fast_tanh(cd1);
            float p0 = ow0[0] * hd0 + ow1[0] * hd1;
            float p1 = ow0[1] * hd0 + ow1[1] * hd1;
            float p2 = ow0[2] * hd0 + ow1[2] * hd1;
            y0 = wave_sum(p0) + ob0;
            y1 = wave_sum(p1) + ob1;
            y2 = wave_sum(p2) + ob2;
            if (lane < 3)
                orow[t * OUTD + lane] = (lane == 0) ? y0 : (lane == 1) ? y1 : y2;
        }
    }
}

extern "C" void kernel_launch(void* const* d_in, const int* in_sizes, int n_in,
                              void* d_out, int out_size, void* d_ws, size_t ws_size,
                              hipStream_t stream) {
    (void)in_sizes; (void)n_in; (void)d_ws; (void)ws_size; (void)out_size;
    enc_dec_kernel<<<512, 512, 0, stream>>>(
        (const float*)d_in[0],
        (const float*)d_in[1], (const float*)d_in[2],
        (const float*)d_in[3], (const float*)d_in[4],
        (const float*)d_in[5], (const float*)d_in[6],
        (const float*)d_in[7], (const float*)d_in[8],
        (const float*)d_in[9], (const float*)d_in[10],
        (float*)d_out);
}

// Round 10
// 291.890 us; speedup vs baseline: 1.9445x; 1.9445x over previous
//
#include <hip/hip_runtime.h>

#define SEQ 288
#define INP 7
#define HID 128
#define TLEN 288
#define OUTD 3
#define XW (SEQ * INP)   // 2016

typedef _Float16 f16x8 __attribute__((ext_vector_type(8)));
typedef float f32x4 __attribute__((ext_vector_type(4)));

__device__ __forceinline__ float fast_sigmoid(float x) {
    float e = __expf(-x);
    return __builtin_amdgcn_rcpf(1.0f + e);
}
__device__ __forceinline__ float fast_tanh(float x) {
    float e = __expf(-2.0f * x);
    return 2.0f * __builtin_amdgcn_rcpf(1.0f + e) - 1.0f;
}

// DPP-based full-wave (64) sum -> uniform scalar.
template<int CTRL, int RM>
__device__ __forceinline__ float dpp_add(float v) {
    int t = __builtin_amdgcn_update_dpp(0, __float_as_int(v), CTRL, RM, 0xF, true);
    return v + __int_as_float(t);
}
__device__ __forceinline__ float wave_sum(float v) {
    v = dpp_add<0xB1, 0xF>(v);   // quad_perm [1,0,3,2]
    v = dpp_add<0x4E, 0xF>(v);   // quad_perm [2,3,0,1]
    v = dpp_add<0x124, 0xF>(v);  // row_ror:4
    v = dpp_add<0x128, 0xF>(v);  // row_ror:8
    v = dpp_add<0x142, 0xA>(v);  // row_bcast15
    v = dpp_add<0x143, 0xC>(v);  // row_bcast31 -> lane63 total
    return __int_as_float(__builtin_amdgcn_readlane(__float_as_int(v), 63));
}

// Redistribute D-fragment (valid rows 0-3 = regs 0-3 of lanes 0-15) so that
// lane L ends up holding the value for (b = L>>4, col = L&15).
// All 64 outputs draw exclusively from lanes 0-15's regs (rows 0-3), so
// garbage in D-rows 4-15 is harmless.
__device__ __forceinline__ float redist4(f32x4 s) {
    int r0 = __float_as_int(s[0]), r1 = __float_as_int(s[1]);
    int r2 = __float_as_int(s[2]), r3 = __float_as_int(s[3]);
    auto p02 = __builtin_amdgcn_permlane32_swap(r0, r2, false, false);
    auto p13 = __builtin_amdgcn_permlane32_swap(r1, r3, false, false);
#if __has_builtin(__builtin_amdgcn_permlane16_swap)
    auto q = __builtin_amdgcn_permlane16_swap(p02[0], p13[0], false, false);
    return __int_as_float(q[0]);
#else
    float n0 = __int_as_float(p02[0]);
    float n1 = __int_as_float(p13[0]);
    int lane = threadIdx.x & 63;
    float tshf = __shfl(n1, lane ^ 16);
    return (lane & 16) ? tshf : n0;
#endif
}

__global__ __launch_bounds__(512, 2)
void enc_dec_kernel(const float* __restrict__ x,
                    const float* __restrict__ eWih, const float* __restrict__ eWhh,
                    const float* __restrict__ ebih, const float* __restrict__ ebhh,
                    const float* __restrict__ dWih, const float* __restrict__ dWhh,
                    const float* __restrict__ dbih, const float* __restrict__ dbhh,
                    const float* __restrict__ oW,  const float* __restrict__ ob,
                    float* __restrict__ out)
{
    // h double-buffer, batch-packed: [dbuf][kc(4)][batch(4)][ke(40 pad)] f16.
    // A-fragment reads use row = col&3 (4-lane same-address broadcast), so
    // MFMA A-rows 4-15 are duplicates of batches 0-3 -> D-rows 4-15 garbage,
    // discarded by redist4.
    __shared__ __align__(16) _Float16 hbuf[2][4][4][40];
    // pre-converted x + constant-1 (bias rider): [t][b][8], j=7 == 1.0
    // +1 pad row so the t+1 prefetch at t=SEQ-1 stays in-bounds.
    __shared__ __align__(16) _Float16 xf16[SEQ + 1][4][8];
    __shared__ float zbl[4][4][HID];   // decoder zbase handoff [gate][b][u]
    __shared__ float cl[4][HID];       // c_enc handoff [b][u]

    const int tid  = threadIdx.x;
    const int wave = tid >> 6;
    const int lane = tid & 63;
    const int col  = lane & 15;        // A-row / B n-col index
    const int grp  = lane >> 4;        // k-chunk 0..3; post-redist: batch row
    const int u    = wave * 16 + col;  // this lane's unit column
    const int bb   = grp;              // this lane's batch row (post-redist)
    const int b0   = blockIdx.x * 4;

    // ---- prologue: zero hbuf + xf16 pad, build xf16 ----
    {
        _Float16* hb = &hbuf[0][0][0][0];
        for (int i = tid; i < 2 * 4 * 4 * 40; i += 512) hb[i] = (_Float16)0.f;
        _Float16* xp = &xf16[SEQ][0][0];
        if (tid < 32) xp[tid] = (_Float16)0.f;
    }
    for (int i = tid; i < 4 * XW; i += 512) {
        int b = i / XW, r = i % XW;
        int t = r / INP, j = r % INP;
        xf16[t][b][j] = (_Float16)x[(size_t)(b0 + b) * XW + r];
    }
    for (int i = tid; i < SEQ * 4; i += 512)
        xf16[i >> 2][i & 3][7] = (_Float16)1.0f;

    // ---- encoder weights as persistent B-fragments ----
    // kc 0..3: Whh (k = kc*32 + grp*8 + e); kc 4: Wih cols j<7, bias at j==7
    f16x8 wfrag[4][5];
    #pragma unroll
    for (int gt = 0; gt < 4; ++gt) {
        const int row = gt * HID + u;
        #pragma unroll
        for (int kc = 0; kc < 4; ++kc) {
            const float* wr = eWhh + (size_t)row * HID + kc * 32 + grp * 8;
            f16x8 wf;
            #pragma unroll
            for (int e = 0; e < 8; ++e) wf[e] = (_Float16)wr[e];
            wfrag[gt][kc] = wf;
        }
        {
            f16x8 wf;
            #pragma unroll
            for (int e = 0; e < 8; ++e) {
                int j = grp * 8 + e;
                float v = 0.f;
                if (j < INP)       v = eWih[(size_t)row * INP + j];
                else if (j == 7)   v = ebih[row] + ebhh[row];
                wf[e] = (_Float16)v;
            }
            wfrag[gt][4] = wf;
        }
    }

    __syncthreads();   // xf16 + hbuf ready

    float cc = 0.f;    // c state for this lane's (bb, u)
    const f32x4 zero = (f32x4){0.f, 0.f, 0.f, 0.f};

    // accX: (x_t @ Wih.T + bias) for the CURRENT step, computed one step ahead.
    f32x4 accX[4];
    {
        f16x8 ax0 = *(const f16x8*)&xf16[0][col & 3][0];
        #pragma unroll
        for (int gt = 0; gt < 4; ++gt)
            accX[gt] = __builtin_amdgcn_mfma_f32_16x16x32_f16(ax0, wfrag[gt][4], zero, 0, 0, 0);
    }

    // ---------------- encoder: 288 steps, unrolled x2 ----------------
    #define ENC_STEP(T, CUR, NXT)                                                     \
    {                                                                                 \
        f16x8 af0 = *(const f16x8*)&hbuf[CUR][0][col & 3][grp * 8];                   \
        f16x8 af1 = *(const f16x8*)&hbuf[CUR][1][col & 3][grp * 8];                   \
        f16x8 af2 = *(const f16x8*)&hbuf[CUR][2][col & 3][grp * 8];                   \
        f16x8 af3 = *(const f16x8*)&hbuf[CUR][3][col & 3][grp * 8];                   \
        f32x4 acc[4];                                                                 \
        _Pragma("unroll")                                                             \
        for (int gt = 0; gt < 4; ++gt) {                                              \
            acc[gt] = __builtin_amdgcn_mfma_f32_16x16x32_f16(af0, wfrag[gt][0], accX[gt], 0, 0, 0); \
            acc[gt] = __builtin_amdgcn_mfma_f32_16x16x32_f16(af1, wfrag[gt][1], acc[gt], 0, 0, 0);  \
            acc[gt] = __builtin_amdgcn_mfma_f32_16x16x32_f16(af2, wfrag[gt][2], acc[gt], 0, 0, 0);  \
            acc[gt] = __builtin_amdgcn_mfma_f32_16x16x32_f16(af3, wfrag[gt][3], acc[gt], 0, 0, 0);  \
        }                                                                             \
        f16x8 axn = *(const f16x8*)&xf16[(T) + 1][col & 3][0];                        \
        _Pragma("unroll")                                                             \
        for (int gt = 0; gt < 4; ++gt)                                                \
            accX[gt] = __builtin_amdgcn_mfma_f32_16x16x32_f16(axn, wfrag[gt][4], zero, 0, 0, 0);    \
        float zi = redist4(acc[0]);                                                   \
        float zf = redist4(acc[1]);                                                   \
        float zg = redist4(acc[2]);                                                   \
        float zo = redist4(acc[3]);                                                   \
        float si = fast_sigmoid(zi);                                                  \
        float sf = fast_sigmoid(zf);                                                  \
        float tg = fast_tanh(zg);                                                     \
        float so = fast_sigmoid(zo);                                                  \
        cc = sf * cc + si * tg;                                                       \
        float h = so * fast_tanh(cc);                                                 \
        hbuf[NXT][u >> 5][bb][u & 31] = (_Float16)h;                                  \
        __syncthreads();                                                              \
    }

    for (int t = 0; t < SEQ; t += 2) {
        ENC_STEP(t, 0, 1)
        ENC_STEP(t + 1, 1, 0)
    }
    #undef ENC_STEP
    // h_enc in hbuf[0]; c_enc = cc per lane (bb, u).

    // ---------------- decoder zbase (all 8 waves) ----------------
    #pragma unroll
    for (int gt = 0; gt < 4; ++gt) {       // reload fragments with dec_Whh
        const int row = gt * HID + u;
        #pragma unroll
        for (int kc = 0; kc < 4; ++kc) {
            const float* wr = dWhh + (size_t)row * HID + kc * 32 + grp * 8;
            f16x8 wf;
            #pragma unroll
            for (int e = 0; e < 8; ++e) wf[e] = (_Float16)wr[e];
            wfrag[gt][kc] = wf;
        }
    }
    {
        f16x8 af0 = *(const f16x8*)&hbuf[0][0][col & 3][grp * 8];
        f16x8 af1 = *(const f16x8*)&hbuf[0][1][col & 3][grp * 8];
        f16x8 af2 = *(const f16x8*)&hbuf[0][2][col & 3][grp * 8];
        f16x8 af3 = *(const f16x8*)&hbuf[0][3][col & 3][grp * 8];
        #pragma unroll
        for (int gt = 0; gt < 4; ++gt) {
            float bd = dbih[gt * HID + u] + dbhh[gt * HID + u];
            f32x4 acc = (f32x4){bd, bd, bd, bd};
            acc = __builtin_amdgcn_mfma_f32_16x16x32_f16(af0, wfrag[gt][0], acc, 0, 0, 0);
            acc = __builtin_amdgcn_mfma_f32_16x16x32_f16(af1, wfrag[gt][1], acc, 0, 0, 0);
            acc = __builtin_amdgcn_mfma_f32_16x16x32_f16(af2, wfrag[gt][2], acc, 0, 0, 0);
            acc = __builtin_amdgcn_mfma_f32_16x16x32_f16(af3, wfrag[gt][3], acc, 0, 0, 0);
            zbl[gt][bb][u] = redist4(acc);
        }
        cl[bb][u] = cc;
    }
    __syncthreads();

    // ---------------- decoder: 1 wave per batch row, no barriers ----------
    if (wave >= 4) return;
    {
        const int b = wave;
        const int u0 = lane, u1 = 64 + lane;
        float zb0[4], zb1[4], wd0[4][3], wd1[4][3];
        #pragma unroll
        for (int gt = 0; gt < 4; ++gt) {
            zb0[gt] = zbl[gt][b][u0];
            zb1[gt] = zbl[gt][b][u1];
            #pragma unroll
            for (int j = 0; j < 3; ++j) {
                wd0[gt][j] = dWih[(size_t)(gt * HID + u0) * 3 + j];
                wd1[gt][j] = dWih[(size_t)(gt * HID + u1) * 3 + j];
            }
        }
        const float c0 = cl[b][u0], c1 = cl[b][u1];
        float ow0[3], ow1[3];
        #pragma unroll
        for (int j = 0; j < 3; ++j) {
            ow0[j] = oW[j * HID + u0];
            ow1[j] = oW[j * HID + u1];
        }
        const float ob0 = ob[0], ob1 = ob[1], ob2 = ob[2];

        float y0 = 0.f, y1 = 0.f, y2 = 0.f;
        float* orow = out + (size_t)(b0 + b) * (TLEN * OUTD);

        for (int t = 0; t < TLEN; ++t) {
            float z0[4], z1[4];
            #pragma unroll
            for (int gt = 0; gt < 4; ++gt) {
                z0[gt] = zb0[gt] + wd0[gt][0] * y0 + wd0[gt][1] * y1 + wd0[gt][2] * y2;
                z1[gt] = zb1[gt] + wd1[gt][0] * y0 + wd1[gt][1] * y1 + wd1[gt][2] * y2;
            }
            float si0 = fast_sigmoid(z0[0]), sf0 = fast_sigmoid(z0[1]);
            float tg0 = fast_tanh(z0[2]),    so0 = fast_sigmoid(z0[3]);
            float si1 = fast_sigmoid(z1[0]), sf1 = fast_sigmoid(z1[1]);
            float tg1 = fast_tanh(z1[2]),    so1 = fast_sigmoid(z1[3]);
            float cd0 = sf0 * c0 + si0 * tg0;
            float cd1 = sf1 * c1 + si1 * tg1;
            float hd0 = so0 * fast_tanh(cd0);
            float hd1 = so1 * fast_tanh(cd1);
            float p0 = ow0[0] * hd0 + ow1[0] * hd1;
            float p1 = ow0[1] * hd0 + ow1[1] * hd1;
            float p2 = ow0[2] * hd0 + ow1[2] * hd1;
            y0 = wave_sum(p0) + ob0;
            y1 = wave_sum(p1) + ob1;
            y2 = wave_sum(p2) + ob2;
            if (lane < 3)
                orow[t * OUTD + lane] = (lane == 0) ? y0 : (lane == 1) ? y1 : y2;
        }
    }
}

extern "C" void kernel_launch(void* const* d_in, const int* in_sizes, int n_in,
                              void* d_out, int out_size, void* d_ws, size_t ws_size,
                              hipStream_t stream) {
    (void)in_sizes; (void)n_in; (void)d_ws; (void)ws_size; (void)out_size;
    enc_dec_kernel<<<256, 512, 0, stream>>>(
        (const float*)d_in[0],
        (const float*)d_in[1], (const float*)d_in[2],
        (const float*)d_in[3], (const float*)d_in[4],
        (const float*)d_in[5], (const float*)d_in[6],
        (const float*)d_in[7], (const float*)d_in[8],
        (const float*)d_in[9], (const float*)d_in[10],
        (float*)d_out);
}

// Round 11
// 258.694 us; speedup vs baseline: 2.1940x; 1.1283x over previous
//
#include <hip/hip_runtime.h>

#define SEQ 288
#define INP 7
#define HID 128
#define TLEN 288
#define OUTD 3
#define XW (SEQ * INP)   // 2016

typedef _Float16 f16x8 __attribute__((ext_vector_type(8)));
typedef float f32x4 __attribute__((ext_vector_type(4)));

#define NLOG2E  (-1.4426950408889634f)   // -log2(e)
#define N2LOG2E (-2.8853900817779268f)   // -2*log2(e)

__device__ __forceinline__ float exp2_fast(float x) {
#if __has_builtin(__builtin_amdgcn_exp2f)
    return __builtin_amdgcn_exp2f(x);
#else
    return __expf(x * 0.69314718056f);
#endif
}
// sigmoid(z) with z' = -log2e*z already applied upstream
__device__ __forceinline__ float sig2(float zp) {
    return __builtin_amdgcn_rcpf(1.0f + exp2_fast(zp));
}
// tanh(z) with z' = -2log2e*z already applied upstream
__device__ __forceinline__ float tanh2(float zp) {
    return 2.0f * __builtin_amdgcn_rcpf(1.0f + exp2_fast(zp)) - 1.0f;
}

// DPP-based full-wave (64) sum -> uniform scalar.
template<int CTRL, int RM>
__device__ __forceinline__ float dpp_add(float v) {
    int t = __builtin_amdgcn_update_dpp(0, __float_as_int(v), CTRL, RM, 0xF, true);
    return v + __int_as_float(t);
}
__device__ __forceinline__ float wave_sum(float v) {
    v = dpp_add<0xB1, 0xF>(v);   // quad_perm [1,0,3,2]
    v = dpp_add<0x4E, 0xF>(v);   // quad_perm [2,3,0,1]
    v = dpp_add<0x124, 0xF>(v);  // row_ror:4
    v = dpp_add<0x128, 0xF>(v);  // row_ror:8
    v = dpp_add<0x142, 0xA>(v);  // row_bcast15
    v = dpp_add<0x143, 0xC>(v);  // row_bcast31 -> lane63 total
    return __int_as_float(__builtin_amdgcn_readlane(__float_as_int(v), 63));
}

// With batch-broadcast A-reads (row = col&3), the D-fragment is PERIODIC:
// every lane's reg r holds z[b=r][its col]. The lane's own (b=grp) value is
// a pure register select — no cross-lane ops.
__device__ __forceinline__ float sel4(f32x4 s, bool m1, bool m2) {
    float a = m1 ? s[1] : s[0];
    float b = m1 ? s[3] : s[2];
    return m2 ? b : a;
}

__global__ __launch_bounds__(512, 2)
void enc_dec_kernel(const float* __restrict__ x,
                    const float* __restrict__ eWih, const float* __restrict__ eWhh,
                    const float* __restrict__ ebih, const float* __restrict__ ebhh,
                    const float* __restrict__ dWih, const float* __restrict__ dWhh,
                    const float* __restrict__ dbih, const float* __restrict__ dbhh,
                    const float* __restrict__ oW,  const float* __restrict__ ob,
                    float* __restrict__ out)
{
    // h double-buffer, batch-packed: [dbuf][kc(4)][batch(4)][ke(40 pad)] f16.
    __shared__ __align__(16) _Float16 hbuf[2][4][4][40];
    // pre-converted x + constant-1 (bias rider): [t][b][8], j=7 == 1.0
    __shared__ __align__(16) _Float16 xf16[SEQ + 1][4][8];
    __shared__ float zbl[4][4][HID];   // decoder zbase handoff [gate][b][u] (SCALED)
    __shared__ float cl[4][HID];       // c_enc handoff [b][u]

    const int tid  = threadIdx.x;
    const int wave = tid >> 6;
    const int lane = tid & 63;
    const int col  = lane & 15;        // A-row / B n-col index
    const int grp  = lane >> 4;        // k-chunk 0..3; also this lane's batch row
    const int u    = wave * 16 + col;  // this lane's unit column
    const int bb   = grp;              // this lane's batch row
    const int b0   = blockIdx.x * 4;
    const bool m1  = (grp & 1) != 0;
    const bool m2  = (grp & 2) != 0;

    // gate scale factors: i,f,o -> -log2e ; g -> -2log2e
    const float GS[4] = {NLOG2E, NLOG2E, N2LOG2E, NLOG2E};

    // ---- prologue: zero hbuf + xf16 pad, build xf16 ----
    {
        _Float16* hb = &hbuf[0][0][0][0];
        for (int i = tid; i < 2 * 4 * 4 * 40; i += 512) hb[i] = (_Float16)0.f;
        _Float16* xp = &xf16[SEQ][0][0];
        if (tid < 32) xp[tid] = (_Float16)0.f;
    }
    for (int i = tid; i < 4 * XW; i += 512) {
        int b = i / XW, r = i % XW;
        int t = r / INP, j = r % INP;
        xf16[t][b][j] = (_Float16)x[(size_t)(b0 + b) * XW + r];
    }
    for (int i = tid; i < SEQ * 4; i += 512)
        xf16[i >> 2][i & 3][7] = (_Float16)1.0f;

    // ---- encoder weights as persistent B-fragments (PRE-SCALED) ----
    // kc 0..3: Whh (k = kc*32 + grp*8 + e); kc 4: Wih cols j<7, bias at j==7
    f16x8 wfrag[4][5];
    #pragma unroll
    for (int gt = 0; gt < 4; ++gt) {
        const int row = gt * HID + u;
        const float gs = GS[gt];
        #pragma unroll
        for (int kc = 0; kc < 4; ++kc) {
            const float* wr = eWhh + (size_t)row * HID + kc * 32 + grp * 8;
            f16x8 wf;
            #pragma unroll
            for (int e = 0; e < 8; ++e) wf[e] = (_Float16)(gs * wr[e]);
            wfrag[gt][kc] = wf;
        }
        {
            f16x8 wf;
            #pragma unroll
            for (int e = 0; e < 8; ++e) {
                int j = grp * 8 + e;
                float v = 0.f;
                if (j < INP)       v = eWih[(size_t)row * INP + j];
                else if (j == 7)   v = ebih[row] + ebhh[row];
                wf[e] = (_Float16)(gs * v);
            }
            wfrag[gt][4] = wf;
        }
    }

    __syncthreads();   // xf16 + hbuf ready

    float cc = 0.f;    // c state for this lane's (bb, u)
    const f32x4 zero = (f32x4){0.f, 0.f, 0.f, 0.f};

    // accX: scaled (x_t @ Wih.T + bias), computed one step ahead.
    f32x4 accX[4];
    {
        f16x8 ax0 = *(const f16x8*)&xf16[0][col & 3][0];
        #pragma unroll
        for (int gt = 0; gt < 4; ++gt)
            accX[gt] = __builtin_amdgcn_mfma_f32_16x16x32_f16(ax0, wfrag[gt][4], zero, 0, 0, 0);
    }

    // ---------------- encoder: 288 steps, unrolled x2 ----------------
    #define ENC_STEP(T, CUR, NXT)                                                     \
    {                                                                                 \
        f16x8 af0 = *(const f16x8*)&hbuf[CUR][0][col & 3][grp * 8];                   \
        f16x8 af1 = *(const f16x8*)&hbuf[CUR][1][col & 3][grp * 8];                   \
        f16x8 af2 = *(const f16x8*)&hbuf[CUR][2][col & 3][grp * 8];                   \
        f16x8 af3 = *(const f16x8*)&hbuf[CUR][3][col & 3][grp * 8];                   \
        f32x4 acc[4];                                                                 \
        _Pragma("unroll")                                                             \
        for (int gt = 0; gt < 4; ++gt) {                                              \
            acc[gt] = __builtin_amdgcn_mfma_f32_16x16x32_f16(af0, wfrag[gt][0], accX[gt], 0, 0, 0); \
            acc[gt] = __builtin_amdgcn_mfma_f32_16x16x32_f16(af1, wfrag[gt][1], acc[gt], 0, 0, 0);  \
            acc[gt] = __builtin_amdgcn_mfma_f32_16x16x32_f16(af2, wfrag[gt][2], acc[gt], 0, 0, 0);  \
            acc[gt] = __builtin_amdgcn_mfma_f32_16x16x32_f16(af3, wfrag[gt][3], acc[gt], 0, 0, 0);  \
        }                                                                             \
        f16x8 axn = *(const f16x8*)&xf16[(T) + 1][col & 3][0];                        \
        _Pragma("unroll")                                                             \
        for (int gt = 0; gt < 4; ++gt)                                                \
            accX[gt] = __builtin_amdgcn_mfma_f32_16x16x32_f16(axn, wfrag[gt][4], zero, 0, 0, 0);    \
        float zi = sel4(acc[0], m1, m2);                                              \
        float zf = sel4(acc[1], m1, m2);                                              \
        float zg = sel4(acc[2], m1, m2);                                              \
        float zo = sel4(acc[3], m1, m2);                                              \
        float si = sig2(zi);                                                          \
        float sf = sig2(zf);                                                          \
        float tg = tanh2(zg);                                                         \
        float so = sig2(zo);                                                          \
        cc = sf * cc + si * tg;                                                       \
        float h = so * tanh2(cc * N2LOG2E);                                           \
        hbuf[NXT][u >> 5][bb][u & 31] = (_Float16)h;                                  \
        __syncthreads();                                                              \
    }

    for (int t = 0; t < SEQ; t += 2) {
        ENC_STEP(t, 0, 1)
        ENC_STEP(t + 1, 1, 0)
    }
    #undef ENC_STEP
    // h_enc in hbuf[0]; c_enc = cc per lane (bb, u).

    // ---------------- decoder zbase (all 8 waves, scaled weights) ----------
    #pragma unroll
    for (int gt = 0; gt < 4; ++gt) {
        const int row = gt * HID + u;
        const float gs = GS[gt];
        #pragma unroll
        for (int kc = 0; kc < 4; ++kc) {
            const float* wr = dWhh + (size_t)row * HID + kc * 32 + grp * 8;
            f16x8 wf;
            #pragma unroll
            for (int e = 0; e < 8; ++e) wf[e] = (_Float16)(gs * wr[e]);
            wfrag[gt][kc] = wf;
        }
    }
    {
        f16x8 af0 = *(const f16x8*)&hbuf[0][0][col & 3][grp * 8];
        f16x8 af1 = *(const f16x8*)&hbuf[0][1][col & 3][grp * 8];
        f16x8 af2 = *(const f16x8*)&hbuf[0][2][col & 3][grp * 8];
        f16x8 af3 = *(const f16x8*)&hbuf[0][3][col & 3][grp * 8];
        #pragma unroll
        for (int gt = 0; gt < 4; ++gt) {
            float bd = GS[gt] * (dbih[gt * HID + u] + dbhh[gt * HID + u]);
            f32x4 acc = (f32x4){bd, bd, bd, bd};
            acc = __builtin_amdgcn_mfma_f32_16x16x32_f16(af0, wfrag[gt][0], acc, 0, 0, 0);
            acc = __builtin_amdgcn_mfma_f32_16x16x32_f16(af1, wfrag[gt][1], acc, 0, 0, 0);
            acc = __builtin_amdgcn_mfma_f32_16x16x32_f16(af2, wfrag[gt][2], acc, 0, 0, 0);
            acc = __builtin_amdgcn_mfma_f32_16x16x32_f16(af3, wfrag[gt][3], acc, 0, 0, 0);
            zbl[gt][bb][u] = sel4(acc, m1, m2);   // scaled z-base
        }
        cl[bb][u] = cc;
    }
    __syncthreads();

    // ---------------- decoder: 1 wave per batch row, no barriers ----------
    if (wave >= 4) return;
    {
        const int b = wave;
        const int u0 = lane, u1 = 64 + lane;
        float zb0[4], zb1[4], wd0[4][3], wd1[4][3];
        #pragma unroll
        for (int gt = 0; gt < 4; ++gt) {
            zb0[gt] = zbl[gt][b][u0];
            zb1[gt] = zbl[gt][b][u1];
            #pragma unroll
            for (int j = 0; j < 3; ++j) {
                wd0[gt][j] = GS[gt] * dWih[(size_t)(gt * HID + u0) * 3 + j];
                wd1[gt][j] = GS[gt] * dWih[(size_t)(gt * HID + u1) * 3 + j];
            }
        }
        const float c0 = cl[b][u0], c1 = cl[b][u1];
        float ow0[3], ow1[3];
        #pragma unroll
        for (int j = 0; j < 3; ++j) {
            ow0[j] = oW[j * HID + u0];
            ow1[j] = oW[j * HID + u1];
        }
        const float ob0 = ob[0], ob1 = ob[1], ob2 = ob[2];

        float y0 = 0.f, y1 = 0.f, y2 = 0.f;
        float* orow = out + (size_t)(b0 + b) * (TLEN * OUTD);

        for (int t = 0; t < TLEN; ++t) {
            float z0[4], z1[4];
            #pragma unroll
            for (int gt = 0; gt < 4; ++gt) {
                z0[gt] = zb0[gt] + wd0[gt][0] * y0 + wd0[gt][1] * y1 + wd0[gt][2] * y2;
                z1[gt] = zb1[gt] + wd1[gt][0] * y0 + wd1[gt][1] * y1 + wd1[gt][2] * y2;
            }
            float si0 = sig2(z0[0]), sf0 = sig2(z0[1]);
            float tg0 = tanh2(z0[2]), so0 = sig2(z0[3]);
            float si1 = sig2(z1[0]), sf1 = sig2(z1[1]);
            float tg1 = tanh2(z1[2]), so1 = sig2(z1[3]);
            float cd0 = sf0 * c0 + si0 * tg0;
            float cd1 = sf1 * c1 + si1 * tg1;
            float hd0 = so0 * tanh2(cd0 * N2LOG2E);
            float hd1 = so1 * tanh2(cd1 * N2LOG2E);
            float p0 = ow0[0] * hd0 + ow1[0] * hd1;
            float p1 = ow0[1] * hd0 + ow1[1] * hd1;
            float p2 = ow0[2] * hd0 + ow1[2] * hd1;
            y0 = wave_sum(p0) + ob0;
            y1 = wave_sum(p1) + ob1;
            y2 = wave_sum(p2) + ob2;
            if (lane < 3)
                orow[t * OUTD + lane] = (lane == 0) ? y0 : (lane == 1) ? y1 : y2;
        }
    }
}

extern "C" void kernel_launch(void* const* d_in, const int* in_sizes, int n_in,
                              void* d_out, int out_size, void* d_ws, size_t ws_size,
                              hipStream_t stream) {
    (void)in_sizes; (void)n_in; (void)d_ws; (void)ws_size; (void)out_size;
    enc_dec_kernel<<<256, 512, 0, stream>>>(
        (const float*)d_in[0],
        (const float*)d_in[1], (const float*)d_in[2],
        (const float*)d_in[3], (const float*)d_in[4],
        (const float*)d_in[5], (const float*)d_in[6],
        (const float*)d_in[7], (const float*)d_in[8],
        (const float*)d_in[9], (const float*)d_in[10],
        (float*)d_out);
}